// Round 7
// baseline (572.673 us; speedup 1.0000x reference)
//
#include <hip/hip_runtime.h>
#include <hip/hip_bf16.h>
#include <math.h>

#define NB 4
#define NN 8192
#define NC 64
#define NK 16
#define BN_SC 0.9999950000375f  // 1/sqrt(1+1e-5)

typedef __bf16 bf16x8 __attribute__((ext_vector_type(8)));
typedef __bf16 bf16x4 __attribute__((ext_vector_type(4)));
typedef float  f32x4  __attribute__((ext_vector_type(4)));

struct BlockParams { const float* a[20]; };
struct TwoParams   { BlockParams p[2]; };

// weight buffer layout per param-block (units of bf16x8 = 16B):
//   tiles 0..23 : mats {dw2,aw1,aw2} x (s*4+ct); 24..27: w1f; 28..35: lwf
// float section at +36*64 units: fb[st*64+ch] st=0..3 biases; fb[256+ch]=lbC
#define WTILES 36
#define WBLK_UNITS (WTILES*64 + 80)

__device__ __forceinline__ f32x4 mfma16(bf16x8 a, bf16x8 b, f32x4 c) {
    return __builtin_amdgcn_mfma_f32_16x16x32_bf16(a, b, c, 0, 0, 0);
}

// ---------------- fused prep: transpose | p-prep | w-prep ----------------
__global__ __launch_bounds__(256) void prep_all_kernel(
    const float* __restrict__ p, const float* __restrict__ x, TwoParams PP,
    float4* __restrict__ pT, float* __restrict__ xT0,
    bf16x8* __restrict__ wbuf, float* __restrict__ out_p)
{
    __shared__ float tile[64][65];
    const int blk = blockIdx.x, tid = threadIdx.x;

    if (blk < 512) {
        int b  = blk >> 7;
        int n0 = (blk & 127) * 64;
        int tl = tid & 63, tw = tid >> 6;
#pragma unroll
        for (int i = 0; i < 16; ++i) {
            int c = tw*16 + i;
            tile[c][tl] = x[((size_t)b*NC + c)*NN + n0 + tl];
        }
        __syncthreads();
#pragma unroll
        for (int i = 0; i < 16; ++i) {
            int nr = tw*16 + i;
            xT0[((size_t)b*NN + n0 + nr)*NC + tl] = tile[tl][nr];
        }
    } else if (blk < 640) {
        int g = (blk - 512)*256 + tid;
        int b = g / NN, n = g % NN;
        float px = p[(b*3+0)*NN + n];
        float py = p[(b*3+1)*NN + n];
        float pz = p[(b*3+2)*NN + n];
        pT[g] = make_float4(px, py, pz, 0.f);
        out_p[(b*3+0)*NN + n] = px;
        out_p[(b*3+1)*NN + n] = py;
        out_p[(b*3+2)*NN + n] = pz;
    } else {
        const BlockParams P = PP.p[blk - 640];
        bf16x8* wbo = wbuf + (size_t)(blk - 640) * WBLK_UNITS;
        const int lane = tid & 63, sub = tid >> 6;
        const int c0 = lane & 15, q = lane >> 4;
        for (int t2 = sub; t2 < WTILES; t2 += 4) {
            bf16x8 v;
            if (t2 < 24) {
                int m = t2 >> 3, st = t2 & 7, s = st >> 2, ct = st & 3;
                const float* W = P.a[4 + m*4];
                const float* g = P.a[6 + m*4];
                int row = ct*16 + c0; float sc = g[row]*BN_SC;
#pragma unroll
                for (int k = 0; k < 8; ++k) v[k] = (__bf16)(W[row*NC + s*32 + q*8 + k]*sc);
            } else if (t2 < 28) {
                int ct = t2 - 24; int row = ct*16 + c0;
                float sc = P.a[2][row]*BN_SC;
#pragma unroll
                for (int k = 0; k < 8; ++k) v[k] = (__bf16)0.f;
                if (q == 0) {
                    v[0] = (__bf16)(P.a[0][row*3+0]*sc);
                    v[1] = (__bf16)(P.a[0][row*3+1]*sc);
                    v[2] = (__bf16)(P.a[0][row*3+2]*sc);
                }
            } else {
                int w = (t2-28) >> 1, s = (t2-28) & 1;
                int ch = w*16 + c0; float sc = P.a[18][ch]*BN_SC;
#pragma unroll
                for (int k = 0; k < 8; ++k) v[k] = (__bf16)(P.a[16][ch*NC + s*32 + q*8 + k]*sc);
            }
            wbo[t2*64 + lane] = v;
        }
        float* fbo = (float*)(wbo + WTILES*64);
        if (tid < 64) {
            int ch = tid;
            fbo[0*64 + ch] = P.a[1][ch]*(P.a[2][ch]*BN_SC)  + P.a[3][ch];
            fbo[1*64 + ch] = P.a[5][ch]*(P.a[6][ch]*BN_SC)  + P.a[7][ch];
            fbo[2*64 + ch] = P.a[9][ch]*(P.a[10][ch]*BN_SC) + P.a[11][ch];
            fbo[3*64 + ch] = P.a[13][ch]*(P.a[14][ch]*BN_SC)+ P.a[15][ch];
            fbo[4*64 + ch] = P.a[17][ch]*(P.a[18][ch]*BN_SC)+ P.a[19][ch];
        }
    }
}

// ---------------- main PT block: 2 tiles/block, prefetched idx/rel --------
__global__ __launch_bounds__(256, 4) void pt_block_kernel(
    const float4* __restrict__ pT,
    const float*  __restrict__ xin,   // (B,N,C)
    const int*    __restrict__ idx,
    const bf16x8* __restrict__ wb,
    float* __restrict__ out,
    int out_chw)
{
    __shared__ alignas(16) __bf16 sb[4][2][16*72];
    __shared__ alignas(16) __bf16 yAll[16*72];

    const int tid = threadIdx.x, wave = tid >> 6, lane = tid & 63;
    const int c0 = lane & 15, quad = lane >> 4;

    const int blk   = blockIdx.x;
    const int b     = blk & 3;          // blk&7 -> XCD; batch pinned to XCD pair
    const int local = blk >> 2;         // 0..255

    const float*  xb = xin + (size_t)b * NN * NC;
    const float4* pb = pT  + (size_t)b * NN;
    const float*  fb = (const float*)(wb + WTILES*64);

    // ---- prefetch BOTH tiles' idx + rel at block start ----
    int jv[2][4];
    __bf16 relb[2][4][3];
#pragma unroll
    for (int t = 0; t < 2; ++t) {
        int n0t = (local + t*256) * 16;
#pragma unroll
        for (int pp = 0; pp < 4; ++pp)
            jv[t][pp] = idx[((size_t)b*NN + n0t + wave*4 + pp)*NK + c0];
#pragma unroll
        for (int pp = 0; pp < 4; ++pp) {
            float4 pn = pb[n0t + wave*4 + pp];
            float4 pj = pb[jv[t][pp]];
            relb[t][pp][0] = (__bf16)(pn.x - pj.x);
            relb[t][pp][1] = (__bf16)(pn.y - pj.y);
            relb[t][pp][2] = (__bf16)(pn.z - pj.z);
        }
    }

    auto load_gxD = [&](int j, float4 (&g)[4]) {
        const float* xr = &xb[(size_t)j * NC];
#pragma unroll
        for (int ct = 0; ct < 4; ++ct)
            g[ct] = *(const float4*)&xr[ct*16 + quad*4];
    };

#pragma unroll 1
    for (int t = 0; t < 2; ++t) {
        const int n0 = (local + t*256) * 16;
        if (t) __syncthreads();   // protect yAll reuse across tiles

        float4 gx0[2][4];
        load_gxD(jv[t][0], gx0[0]);
        load_gxD(jv[t][1], gx0[1]);

        auto run_group = [&](int g, float4 (&gxD)[2][4]) {
            __bf16* buf0 = sb[wave][0];
            __bf16* buf1 = sb[wave][1];

            // stage 1 (swapped): h1 = relu(W1 @ rel + b1), D=[ch][nb]
            {
                bf16x8 afr[2];
#pragma unroll
                for (int pt = 0; pt < 2; ++pt) {
#pragma unroll
                    for (int k = 0; k < 8; ++k) afr[pt][k] = (__bf16)0.f;
                    if (quad == 0) {
                        afr[pt][0] = relb[t][g*2+pt][0];
                        afr[pt][1] = relb[t][g*2+pt][1];
                        afr[pt][2] = relb[t][g*2+pt][2];
                    }
                }
#pragma unroll
                for (int ct = 0; ct < 4; ++ct) {
                    bf16x8 w = wb[(24+ct)*64 + lane];
                    float4 bv = *(const float4*)&fb[0*64 + ct*16 + quad*4];
#pragma unroll
                    for (int pt = 0; pt < 2; ++pt) {
                        f32x4 a;
#pragma unroll
                        for (int r = 0; r < 4; ++r) a[r] = ((const float*)&bv)[r];
                        a = mfma16(w, afr[pt], a);
                        bf16x4 pk;
#pragma unroll
                        for (int r = 0; r < 4; ++r) pk[r] = (__bf16)fmaxf(a[r], 0.f);
                        *(bf16x4*)&(pt ? buf1 : buf0)[c0*72 + ct*16 + quad*4] = pk;
                    }
                }
            }
            // stage 2 (swapped): t2 = W2 @ h1 + b2 + gx (gx in acc init)
            {
                bf16x8 f0[2], f1[2];
                f0[0] = *(const bf16x8*)&buf0[c0*72 + quad*8];
                f1[0] = *(const bf16x8*)&buf0[c0*72 + 32 + quad*8];
                f0[1] = *(const bf16x8*)&buf1[c0*72 + quad*8];
                f1[1] = *(const bf16x8*)&buf1[c0*72 + 32 + quad*8];
#pragma unroll
                for (int ct = 0; ct < 4; ++ct) {
                    bf16x8 w0 = wb[(0+ct)*64 + lane];
                    bf16x8 w1 = wb[(4+ct)*64 + lane];
                    float4 bv = *(const float4*)&fb[1*64 + ct*16 + quad*4];
#pragma unroll
                    for (int pt = 0; pt < 2; ++pt) {
                        f32x4 a;
#pragma unroll
                        for (int r = 0; r < 4; ++r)
                            a[r] = ((const float*)&bv)[r] + ((const float*)&gxD[pt][ct])[r];
                        a = mfma16(w0, f0[pt], a);
                        a = mfma16(w1, f1[pt], a);
                        bf16x4 pk;
#pragma unroll
                        for (int r = 0; r < 4; ++r) pk[r] = (__bf16)a[r];
                        *(bf16x4*)&(pt ? buf1 : buf0)[c0*72 + ct*16 + quad*4] = pk;
                    }
                }
            }
            // stage 3 (swapped): a1 = relu(A1 @ t2 + b3)
            {
                bf16x8 f0[2], f1[2];
                f0[0] = *(const bf16x8*)&buf0[c0*72 + quad*8];
                f1[0] = *(const bf16x8*)&buf0[c0*72 + 32 + quad*8];
                f0[1] = *(const bf16x8*)&buf1[c0*72 + quad*8];
                f1[1] = *(const bf16x8*)&buf1[c0*72 + 32 + quad*8];
#pragma unroll
                for (int ct = 0; ct < 4; ++ct) {
                    bf16x8 w0 = wb[( 8+ct)*64 + lane];
                    bf16x8 w1 = wb[(12+ct)*64 + lane];
                    float4 bv = *(const float4*)&fb[2*64 + ct*16 + quad*4];
#pragma unroll
                    for (int pt = 0; pt < 2; ++pt) {
                        f32x4 a;
#pragma unroll
                        for (int r = 0; r < 4; ++r) a[r] = ((const float*)&bv)[r];
                        a = mfma16(w0, f0[pt], a);
                        a = mfma16(w1, f1[pt], a);
                        bf16x4 pk;
#pragma unroll
                        for (int r = 0; r < 4; ++r) pk[r] = (__bf16)fmaxf(a[r], 0.f);
                        *(bf16x4*)&(pt ? buf1 : buf0)[c0*72 + ct*16 + quad*4] = pk;
                    }
                }
            }
            // stage 4 (normal): a2 = relu(A2 @ a1 + b4); max over nb
            {
                bf16x8 f0[2], f1[2];
                f0[0] = *(const bf16x8*)&buf0[c0*72 + quad*8];
                f1[0] = *(const bf16x8*)&buf0[c0*72 + 32 + quad*8];
                f0[1] = *(const bf16x8*)&buf1[c0*72 + quad*8];
                f1[1] = *(const bf16x8*)&buf1[c0*72 + 32 + quad*8];
                float mx[2][4];
#pragma unroll
                for (int ct = 0; ct < 4; ++ct) {
                    bf16x8 w0 = wb[(16+ct)*64 + lane];
                    bf16x8 w1 = wb[(20+ct)*64 + lane];
                    float bc = fb[3*64 + ct*16 + c0];
#pragma unroll
                    for (int pt = 0; pt < 2; ++pt) {
                        f32x4 a;
#pragma unroll
                        for (int r = 0; r < 4; ++r) a[r] = bc;
                        a = mfma16(f0[pt], w0, a);
                        a = mfma16(f1[pt], w1, a);
                        float m = 0.f;  // relu floor
#pragma unroll
                        for (int r = 0; r < 4; ++r) m = fmaxf(m, a[r]);
                        mx[pt][ct] = m;
                    }
                }
#pragma unroll
                for (int pt = 0; pt < 2; ++pt) {
                    float m0 = mx[pt][0], m1 = mx[pt][1], m2 = mx[pt][2], m3 = mx[pt][3];
                    m0 = fmaxf(m0, __shfl_xor(m0, 16, 64));
                    m0 = fmaxf(m0, __shfl_xor(m0, 32, 64));
                    m1 = fmaxf(m1, __shfl_xor(m1, 16, 64));
                    m1 = fmaxf(m1, __shfl_xor(m1, 32, 64));
                    m2 = fmaxf(m2, __shfl_xor(m2, 16, 64));
                    m2 = fmaxf(m2, __shfl_xor(m2, 32, 64));
                    m3 = fmaxf(m3, __shfl_xor(m3, 16, 64));
                    m3 = fmaxf(m3, __shfl_xor(m3, 32, 64));
                    float mq = (quad == 0) ? m0 : (quad == 1) ? m1 : (quad == 2) ? m2 : m3;
                    yAll[(wave*4 + g*2 + pt)*72 + quad*16 + c0] = (__bf16)mq;
                }
            }
        };

        run_group(0, gx0);

        float4 gx1[2][4];
        load_gxD(jv[t][2], gx1[0]);
        load_gxD(jv[t][3], gx1[1]);
        asm volatile("" ::: "memory");   // block weight-load hoisting across groups
        run_group(1, gx1);

        __syncthreads();

        // down-proj (swapped): D=[ch][pt]; residual in acc init
        {
            bf16x8 y0  = *(const bf16x8*)&yAll[c0*72 + quad*8];
            bf16x8 y1  = *(const bf16x8*)&yAll[c0*72 + 32 + quad*8];
            bf16x8 lw0 = wb[(28 + wave*2 + 0)*64 + lane];
            bf16x8 lw1 = wb[(28 + wave*2 + 1)*64 + lane];
            float4 lb4 = *(const float4*)&fb[4*64 + wave*16 + quad*4];
            float4 res = *(const float4*)&xb[(size_t)(n0 + c0)*NC + wave*16 + quad*4];
            f32x4 a;
#pragma unroll
            for (int r = 0; r < 4; ++r)
                a[r] = ((const float*)&lb4)[r] + ((const float*)&res)[r];
            a = mfma16(lw0, y0, a);
            a = mfma16(lw1, y1, a);

            if (out_chw) {
#pragma unroll
                for (int r = 0; r < 4; ++r)
                    out[((size_t)b*NC + wave*16 + quad*4 + r)*NN + n0 + c0] = a[r];
            } else {
                float4 v = make_float4(a[0], a[1], a[2], a[3]);
                *(float4*)&out[((size_t)b*NN + n0 + c0)*NC + wave*16 + quad*4] = v;
            }
        }
    }
}

extern "C" void kernel_launch(void* const* d_in, const int* in_sizes, int n_in,
                              void* d_out, int out_size, void* d_ws, size_t ws_size,
                              hipStream_t stream) {
    (void)in_sizes; (void)n_in; (void)out_size; (void)ws_size;
    const float* p   = (const float*)d_in[0];
    const float* x   = (const float*)d_in[1];
    const int*   idx = (const int*)d_in[2];

    float* pT  = (float*)d_ws;                          // NB*NN*4 floats
    float* xT0 = pT  + (size_t)NB*NN*4;                 // NB*NN*NC
    float* xT1 = xT0 + (size_t)NB*NN*NC;                // NB*NN*NC
    bf16x8* wbuf = (bf16x8*)(xT1 + (size_t)NB*NN*NC);   // 2 * WBLK_UNITS

    float* out_p = (float*)d_out;                       // (B,3,N)
    float* out_x = out_p + (size_t)NB*3*NN;             // (B,C,N)

    static const int strd[20] = {192,64,64,64, 4096,64,64,64,
                                 4096,64,64,64, 4096,64,64,64,
                                 4096,64,64,64};
    TwoParams PP;
    for (int i = 0; i < 20; ++i) {
        const float* base = (const float*)d_in[3+i];
        PP.p[0].a[i] = base;
        PP.p[1].a[i] = base + strd[i];
    }

    prep_all_kernel<<<642, 256, 0, stream>>>(p, x, PP, (float4*)pT, xT0, wbuf, out_p);
    pt_block_kernel<<<NB*NN/32, 256, 0, stream>>>((const float4*)pT, xT0, idx,
                                                  wbuf, xT1, 0);
    pt_block_kernel<<<NB*NN/32, 256, 0, stream>>>((const float4*)pT, xT1, idx,
                                                  wbuf + WBLK_UNITS, out_x, 1);
}

// Round 8
// 193.037 us; speedup vs baseline: 2.9667x; 2.9667x over previous
//
#include <hip/hip_runtime.h>
#include <hip/hip_bf16.h>
#include <math.h>

#define NB 4
#define NN 8192
#define NC 64
#define NK 16
#define BN_SC 0.9999950000375f  // 1/sqrt(1+1e-5)

typedef __bf16 bf16x8 __attribute__((ext_vector_type(8)));
typedef __bf16 bf16x4 __attribute__((ext_vector_type(4)));
typedef float  f32x4  __attribute__((ext_vector_type(4)));

struct BlockParams { const float* a[20]; };
struct TwoParams   { BlockParams p[2]; };

// weight buffer layout per param-block (units of bf16x8 = 16B):
//   tiles 0..23 : mats {dw2,aw1,aw2} x (s*4+ct); 24..27: w1f; 28..35: lwf
// float section at +36*64 units: fb[st*64+ch] st=0..3 biases; fb[256+ch]=lbC
#define WTILES 36
#define WBLK_UNITS (WTILES*64 + 80)

__device__ __forceinline__ f32x4 mfma16(bf16x8 a, bf16x8 b, f32x4 c) {
    return __builtin_amdgcn_mfma_f32_16x16x32_bf16(a, b, c, 0, 0, 0);
}

// ---------------- fused prep: transpose | p-prep | w-prep ----------------
__global__ __launch_bounds__(256) void prep_all_kernel(
    const float* __restrict__ p, const float* __restrict__ x, TwoParams PP,
    float4* __restrict__ pT, float* __restrict__ xT0,
    bf16x8* __restrict__ wbuf, float* __restrict__ out_p)
{
    __shared__ float tile[64][65];
    const int blk = blockIdx.x, tid = threadIdx.x;

    if (blk < 512) {
        int b  = blk >> 7;
        int n0 = (blk & 127) * 64;
        int tl = tid & 63, tw = tid >> 6;
#pragma unroll
        for (int i = 0; i < 16; ++i) {
            int c = tw*16 + i;
            tile[c][tl] = x[((size_t)b*NC + c)*NN + n0 + tl];
        }
        __syncthreads();
#pragma unroll
        for (int i = 0; i < 16; ++i) {
            int nr = tw*16 + i;
            xT0[((size_t)b*NN + n0 + nr)*NC + tl] = tile[tl][nr];
        }
    } else if (blk < 640) {
        int g = (blk - 512)*256 + tid;
        int b = g / NN, n = g % NN;
        float px = p[(b*3+0)*NN + n];
        float py = p[(b*3+1)*NN + n];
        float pz = p[(b*3+2)*NN + n];
        pT[g] = make_float4(px, py, pz, 0.f);
        out_p[(b*3+0)*NN + n] = px;
        out_p[(b*3+1)*NN + n] = py;
        out_p[(b*3+2)*NN + n] = pz;
    } else {
        const BlockParams P = PP.p[blk - 640];
        bf16x8* wbo = wbuf + (size_t)(blk - 640) * WBLK_UNITS;
        const int lane = tid & 63, sub = tid >> 6;
        const int c0 = lane & 15, q = lane >> 4;
        for (int t2 = sub; t2 < WTILES; t2 += 4) {
            bf16x8 v;
            if (t2 < 24) {
                int m = t2 >> 3, st = t2 & 7, s = st >> 2, ct = st & 3;
                const float* W = P.a[4 + m*4];
                const float* g = P.a[6 + m*4];
                int row = ct*16 + c0; float sc = g[row]*BN_SC;
#pragma unroll
                for (int k = 0; k < 8; ++k) v[k] = (__bf16)(W[row*NC + s*32 + q*8 + k]*sc);
            } else if (t2 < 28) {
                int ct = t2 - 24; int row = ct*16 + c0;
                float sc = P.a[2][row]*BN_SC;
#pragma unroll
                for (int k = 0; k < 8; ++k) v[k] = (__bf16)0.f;
                if (q == 0) {
                    v[0] = (__bf16)(P.a[0][row*3+0]*sc);
                    v[1] = (__bf16)(P.a[0][row*3+1]*sc);
                    v[2] = (__bf16)(P.a[0][row*3+2]*sc);
                }
            } else {
                int w = (t2-28) >> 1, s = (t2-28) & 1;
                int ch = w*16 + c0; float sc = P.a[18][ch]*BN_SC;
#pragma unroll
                for (int k = 0; k < 8; ++k) v[k] = (__bf16)(P.a[16][ch*NC + s*32 + q*8 + k]*sc);
            }
            wbo[t2*64 + lane] = v;
        }
        float* fbo = (float*)(wbo + WTILES*64);
        if (tid < 64) {
            int ch = tid;
            fbo[0*64 + ch] = P.a[1][ch]*(P.a[2][ch]*BN_SC)  + P.a[3][ch];
            fbo[1*64 + ch] = P.a[5][ch]*(P.a[6][ch]*BN_SC)  + P.a[7][ch];
            fbo[2*64 + ch] = P.a[9][ch]*(P.a[10][ch]*BN_SC) + P.a[11][ch];
            fbo[3*64 + ch] = P.a[13][ch]*(P.a[14][ch]*BN_SC)+ P.a[15][ch];
            fbo[4*64 + ch] = P.a[17][ch]*(P.a[18][ch]*BN_SC)+ P.a[19][ch];
        }
    }
}

// ---------------- main PT block: 4 points/stage single pass ----------------
__global__ __launch_bounds__(256, 4) void pt_block_kernel(
    const float4* __restrict__ pT,
    const float*  __restrict__ xin,   // (B,N,C)
    const int*    __restrict__ idx,
    const bf16x8* __restrict__ wb,
    float* __restrict__ out,
    int out_chw)
{
    __shared__ alignas(16) __bf16 sb[4][4][16*72];   // per wave, per point
    __shared__ alignas(16) __bf16 yAll[16*72];

    const int tid = threadIdx.x, wave = tid >> 6, lane = tid & 63;
    const int c0 = lane & 15, quad = lane >> 4;

    const int x  = blockIdx.x;
    const int b  = x & 3;
    const int n0 = ((((x >> 2) & 1) << 8) | (x >> 3)) * 16;

    const float*  xb = xin + (size_t)b * NN * NC;
    const float4* pb = pT  + (size_t)b * NN;
    const float*  fb = (const float*)(wb + WTILES*64);

    int jv[4];
#pragma unroll
    for (int pp = 0; pp < 4; ++pp)
        jv[pp] = idx[((size_t)b*NN + n0 + wave*4 + pp)*NK + c0];

    // rel -> A-fragment directly (relb dies into afr)
    bf16x8 afr[4];
#pragma unroll
    for (int pp = 0; pp < 4; ++pp) {
        float4 pn = pb[n0 + wave*4 + pp];
        float4 pj = pb[jv[pp]];
#pragma unroll
        for (int k = 0; k < 8; ++k) afr[pp][k] = (__bf16)0.f;
        if (quad == 0) {
            afr[pp][0] = (__bf16)(pn.x - pj.x);
            afr[pp][1] = (__bf16)(pn.y - pj.y);
            afr[pp][2] = (__bf16)(pn.z - pj.z);
        }
    }

    // gx gathers in D-layout, held as bf16x4 (32 VGPR); issued here so the
    // ~200-400cyc L2 latency hides behind stage 1
    bf16x4 gxb[4][4];
#pragma unroll
    for (int pt = 0; pt < 4; ++pt) {
        const float* xr = &xb[(size_t)jv[pt] * NC];
#pragma unroll
        for (int ct = 0; ct < 4; ++ct) {
            float4 q = *(const float4*)&xr[ct*16 + quad*4];
            gxb[pt][ct][0] = (__bf16)q.x; gxb[pt][ct][1] = (__bf16)q.y;
            gxb[pt][ct][2] = (__bf16)q.z; gxb[pt][ct][3] = (__bf16)q.w;
        }
    }

    // ---- stage 1 (swapped): h1 = relu(W1 @ rel + b1), D=[ch][nb] ----
#pragma unroll
    for (int ct = 0; ct < 4; ++ct) {
        bf16x8 w = wb[(24+ct)*64 + lane];
        float4 bv = *(const float4*)&fb[0*64 + ct*16 + quad*4];
#pragma unroll
        for (int pt = 0; pt < 4; ++pt) {
            f32x4 a;
#pragma unroll
            for (int r = 0; r < 4; ++r) a[r] = ((const float*)&bv)[r];
            a = mfma16(w, afr[pt], a);
            bf16x4 pk;
#pragma unroll
            for (int r = 0; r < 4; ++r) pk[r] = (__bf16)fmaxf(a[r], 0.f);
            *(bf16x4*)&sb[wave][pt][c0*72 + ct*16 + quad*4] = pk;
        }
    }

    // ---- stage 2 (swapped): t = W2 @ h1 + b2 + gx (gx in acc init) ----
    {
        bf16x8 f0[4], f1[4];
#pragma unroll
        for (int pt = 0; pt < 4; ++pt) {
            f0[pt] = *(const bf16x8*)&sb[wave][pt][c0*72 + quad*8];
            f1[pt] = *(const bf16x8*)&sb[wave][pt][c0*72 + 32 + quad*8];
        }
#pragma unroll
        for (int ct = 0; ct < 4; ++ct) {
            bf16x8 w0 = wb[(0+ct)*64 + lane];
            bf16x8 w1 = wb[(4+ct)*64 + lane];
            float4 bv = *(const float4*)&fb[1*64 + ct*16 + quad*4];
#pragma unroll
            for (int pt = 0; pt < 4; ++pt) {
                f32x4 a;
#pragma unroll
                for (int r = 0; r < 4; ++r)
                    a[r] = ((const float*)&bv)[r] + (float)gxb[pt][ct][r];
                a = mfma16(w0, f0[pt], a);
                a = mfma16(w1, f1[pt], a);
                bf16x4 pk;
#pragma unroll
                for (int r = 0; r < 4; ++r) pk[r] = (__bf16)a[r];
                *(bf16x4*)&sb[wave][pt][c0*72 + ct*16 + quad*4] = pk;
            }
        }
    }

    // ---- stage 3 (swapped): a1 = relu(A1 @ t + b3) ----
    {
        bf16x8 f0[4], f1[4];
#pragma unroll
        for (int pt = 0; pt < 4; ++pt) {
            f0[pt] = *(const bf16x8*)&sb[wave][pt][c0*72 + quad*8];
            f1[pt] = *(const bf16x8*)&sb[wave][pt][c0*72 + 32 + quad*8];
        }
#pragma unroll
        for (int ct = 0; ct < 4; ++ct) {
            bf16x8 w0 = wb[( 8+ct)*64 + lane];
            bf16x8 w1 = wb[(12+ct)*64 + lane];
            float4 bv = *(const float4*)&fb[2*64 + ct*16 + quad*4];
#pragma unroll
            for (int pt = 0; pt < 4; ++pt) {
                f32x4 a;
#pragma unroll
                for (int r = 0; r < 4; ++r) a[r] = ((const float*)&bv)[r];
                a = mfma16(w0, f0[pt], a);
                a = mfma16(w1, f1[pt], a);
                bf16x4 pk;
#pragma unroll
                for (int r = 0; r < 4; ++r) pk[r] = (__bf16)fmaxf(a[r], 0.f);
                *(bf16x4*)&sb[wave][pt][c0*72 + ct*16 + quad*4] = pk;
            }
        }
    }

    // ---- stage 4 (normal): a2 = relu(A2 @ a1 + b4); max over nb ----
    {
        bf16x8 f0[4], f1[4];
#pragma unroll
        for (int pt = 0; pt < 4; ++pt) {
            f0[pt] = *(const bf16x8*)&sb[wave][pt][c0*72 + quad*8];
            f1[pt] = *(const bf16x8*)&sb[wave][pt][c0*72 + 32 + quad*8];
        }
        float mx[4][4];
#pragma unroll
        for (int ct = 0; ct < 4; ++ct) {
            bf16x8 w0 = wb[(16+ct)*64 + lane];
            bf16x8 w1 = wb[(20+ct)*64 + lane];
            float bc = fb[3*64 + ct*16 + c0];
#pragma unroll
            for (int pt = 0; pt < 4; ++pt) {
                f32x4 a;
#pragma unroll
                for (int r = 0; r < 4; ++r) a[r] = bc;
                a = mfma16(f0[pt], w0, a);
                a = mfma16(f1[pt], w1, a);
                float m = 0.f;  // relu floor
#pragma unroll
                for (int r = 0; r < 4; ++r) m = fmaxf(m, a[r]);
                mx[pt][ct] = m;
            }
        }
#pragma unroll
        for (int pt = 0; pt < 4; ++pt) {
            float m0 = mx[pt][0], m1 = mx[pt][1], m2 = mx[pt][2], m3 = mx[pt][3];
            m0 = fmaxf(m0, __shfl_xor(m0, 16, 64));
            m0 = fmaxf(m0, __shfl_xor(m0, 32, 64));
            m1 = fmaxf(m1, __shfl_xor(m1, 16, 64));
            m1 = fmaxf(m1, __shfl_xor(m1, 32, 64));
            m2 = fmaxf(m2, __shfl_xor(m2, 16, 64));
            m2 = fmaxf(m2, __shfl_xor(m2, 32, 64));
            m3 = fmaxf(m3, __shfl_xor(m3, 16, 64));
            m3 = fmaxf(m3, __shfl_xor(m3, 32, 64));
            float mq = (quad == 0) ? m0 : (quad == 1) ? m1 : (quad == 2) ? m2 : m3;
            yAll[(wave*4 + pt)*72 + quad*16 + c0] = (__bf16)mq;
        }
    }

    __syncthreads();

    // ---- down-proj (swapped): D=[ch][pt]; residual in acc init ----
    {
        bf16x8 y0  = *(const bf16x8*)&yAll[c0*72 + quad*8];
        bf16x8 y1  = *(const bf16x8*)&yAll[c0*72 + 32 + quad*8];
        bf16x8 lw0 = wb[(28 + wave*2 + 0)*64 + lane];
        bf16x8 lw1 = wb[(28 + wave*2 + 1)*64 + lane];
        float4 lb4 = *(const float4*)&fb[4*64 + wave*16 + quad*4];
        float4 res = *(const float4*)&xb[(size_t)(n0 + c0)*NC + wave*16 + quad*4];
        f32x4 a;
#pragma unroll
        for (int r = 0; r < 4; ++r)
            a[r] = ((const float*)&lb4)[r] + ((const float*)&res)[r];
        a = mfma16(lw0, y0, a);
        a = mfma16(lw1, y1, a);

        if (out_chw) {
#pragma unroll
            for (int r = 0; r < 4; ++r)
                out[((size_t)b*NC + wave*16 + quad*4 + r)*NN + n0 + c0] = a[r];
        } else {
            float4 v = make_float4(a[0], a[1], a[2], a[3]);
            *(float4*)&out[((size_t)b*NN + n0 + c0)*NC + wave*16 + quad*4] = v;
        }
    }
}

extern "C" void kernel_launch(void* const* d_in, const int* in_sizes, int n_in,
                              void* d_out, int out_size, void* d_ws, size_t ws_size,
                              hipStream_t stream) {
    (void)in_sizes; (void)n_in; (void)out_size; (void)ws_size;
    const float* p   = (const float*)d_in[0];
    const float* x   = (const float*)d_in[1];
    const int*   idx = (const int*)d_in[2];

    float* pT  = (float*)d_ws;                          // NB*NN*4 floats
    float* xT0 = pT  + (size_t)NB*NN*4;                 // NB*NN*NC
    float* xT1 = xT0 + (size_t)NB*NN*NC;                // NB*NN*NC
    bf16x8* wbuf = (bf16x8*)(xT1 + (size_t)NB*NN*NC);   // 2 * WBLK_UNITS

    float* out_p = (float*)d_out;                       // (B,3,N)
    float* out_x = out_p + (size_t)NB*3*NN;             // (B,C,N)

    static const int strd[20] = {192,64,64,64, 4096,64,64,64,
                                 4096,64,64,64, 4096,64,64,64,
                                 4096,64,64,64};
    TwoParams PP;
    for (int i = 0; i < 20; ++i) {
        const float* base = (const float*)d_in[3+i];
        PP.p[0].a[i] = base;
        PP.p[1].a[i] = base + strd[i];
    }

    prep_all_kernel<<<642, 256, 0, stream>>>(p, x, PP, (float4*)pT, xT0, wbuf, out_p);
    pt_block_kernel<<<NB*NN/16, 256, 0, stream>>>((const float4*)pT, xT0, idx,
                                                  wbuf, xT1, 0);
    pt_block_kernel<<<NB*NN/16, 256, 0, stream>>>((const float4*)pT, xT1, idx,
                                                  wbuf + WBLK_UNITS, out_x, 1);
}

// Round 9
// 179.691 us; speedup vs baseline: 3.1870x; 1.0743x over previous
//
#include <hip/hip_runtime.h>
#include <hip/hip_bf16.h>
#include <math.h>

#define NB 4
#define NN 8192
#define NC 64
#define NK 16
#define BN_SC 0.9999950000375f  // 1/sqrt(1+1e-5)

typedef __bf16 bf16x8 __attribute__((ext_vector_type(8)));
typedef __bf16 bf16x4 __attribute__((ext_vector_type(4)));
typedef float  f32x4  __attribute__((ext_vector_type(4)));

struct BlockParams { const float* a[20]; };
struct TwoParams   { BlockParams p[2]; };

// weight buffer layout per param-block (units of bf16x8 = 16B):
//   tiles 0..23 : mats {dw2,aw1,aw2} x (s*4+ct); 24..27: w1f (k=3 carries bias,
//   pairs with A-frag k=3 == 1.0); 28..35: lwf
// float section at +36*64 units: fb[st*64+ch] st=0..3 biases (st0 unused now);
//   fb[256+ch]=lbC
#define WTILES 36
#define WBLK_UNITS (WTILES*64 + 80)

__device__ __forceinline__ f32x4 mfma16(bf16x8 a, bf16x8 b, f32x4 c) {
    return __builtin_amdgcn_mfma_f32_16x16x32_bf16(a, b, c, 0, 0, 0);
}

// ---------------- fused prep: transpose->bf16 | p-prep | w-prep -----------
__global__ __launch_bounds__(256) void prep_all_kernel(
    const float* __restrict__ p, const float* __restrict__ x, TwoParams PP,
    float4* __restrict__ pT, __bf16* __restrict__ xT0,
    bf16x8* __restrict__ wbuf, float* __restrict__ out_p)
{
    __shared__ float tile[64][65];
    const int blk = blockIdx.x, tid = threadIdx.x;

    if (blk < 512) {
        int b  = blk >> 7;
        int n0 = (blk & 127) * 64;
        int tl = tid & 63, tw = tid >> 6;
#pragma unroll
        for (int i = 0; i < 16; ++i) {
            int c = tw*16 + i;
            tile[c][tl] = x[((size_t)b*NC + c)*NN + n0 + tl];
        }
        __syncthreads();
#pragma unroll
        for (int i = 0; i < 16; ++i) {
            int nr = tw*16 + i;
            xT0[((size_t)b*NN + n0 + nr)*NC + tl] = (__bf16)tile[tl][nr];
        }
    } else if (blk < 640) {
        int g = (blk - 512)*256 + tid;
        int b = g / NN, n = g % NN;
        float px = p[(b*3+0)*NN + n];
        float py = p[(b*3+1)*NN + n];
        float pz = p[(b*3+2)*NN + n];
        pT[g] = make_float4(px, py, pz, 0.f);
        out_p[(b*3+0)*NN + n] = px;
        out_p[(b*3+1)*NN + n] = py;
        out_p[(b*3+2)*NN + n] = pz;
    } else {
        const BlockParams P = PP.p[blk - 640];
        bf16x8* wbo = wbuf + (size_t)(blk - 640) * WBLK_UNITS;
        const int lane = tid & 63, sub = tid >> 6;
        const int c0 = lane & 15, q = lane >> 4;
        for (int t2 = sub; t2 < WTILES; t2 += 4) {
            bf16x8 v;
            if (t2 < 24) {
                int m = t2 >> 3, st = t2 & 7, s = st >> 2, ct = st & 3;
                const float* W = P.a[4 + m*4];
                const float* g = P.a[6 + m*4];
                int row = ct*16 + c0; float sc = g[row]*BN_SC;
#pragma unroll
                for (int k = 0; k < 8; ++k) v[k] = (__bf16)(W[row*NC + s*32 + q*8 + k]*sc);
            } else if (t2 < 28) {
                int ct = t2 - 24; int row = ct*16 + c0;
                float sc = P.a[2][row]*BN_SC;
#pragma unroll
                for (int k = 0; k < 8; ++k) v[k] = (__bf16)0.f;
                if (q == 0) {
                    v[0] = (__bf16)(P.a[0][row*3+0]*sc);
                    v[1] = (__bf16)(P.a[0][row*3+1]*sc);
                    v[2] = (__bf16)(P.a[0][row*3+2]*sc);
                    // bias rides k=3 (A-frag k=3 is 1.0)
                    v[3] = (__bf16)(P.a[1][row]*sc + P.a[3][row]);
                }
            } else {
                int w = (t2-28) >> 1, s = (t2-28) & 1;
                int ch = w*16 + c0; float sc = P.a[18][ch]*BN_SC;
#pragma unroll
                for (int k = 0; k < 8; ++k) v[k] = (__bf16)(P.a[16][ch*NC + s*32 + q*8 + k]*sc);
            }
            wbo[t2*64 + lane] = v;
        }
        float* fbo = (float*)(wbo + WTILES*64);
        if (tid < 64) {
            int ch = tid;
            fbo[0*64 + ch] = 0.f;   // stage-1 bias now in weight k=3
            fbo[1*64 + ch] = P.a[5][ch]*(P.a[6][ch]*BN_SC)  + P.a[7][ch];
            fbo[2*64 + ch] = P.a[9][ch]*(P.a[10][ch]*BN_SC) + P.a[11][ch];
            fbo[3*64 + ch] = P.a[13][ch]*(P.a[14][ch]*BN_SC)+ P.a[15][ch];
            fbo[4*64 + ch] = P.a[17][ch]*(P.a[18][ch]*BN_SC)+ P.a[19][ch];
        }
    }
}

// ---------------- main PT block: 4 points/stage, bf16 activations ---------
// CHW=0: out is bf16 (B,N,C) workspace; CHW=1: out is f32 (B,C,N) d_out.
template<int CHW>
__global__ __launch_bounds__(256, 4) void pt_block_kernel(
    const float4* __restrict__ pT,
    const __bf16* __restrict__ xin,   // (B,N,C) bf16
    const int*    __restrict__ idx,
    const bf16x8* __restrict__ wb,
    void* __restrict__ outv)
{
    __shared__ alignas(16) __bf16 sb[4][4][16*72];   // per wave, per point
    __shared__ alignas(16) __bf16 yAll[16*72];

    const int tid = threadIdx.x, wave = tid >> 6, lane = tid & 63;
    const int c0 = lane & 15, quad = lane >> 4;

    const int x  = blockIdx.x;
    const int b  = x & 3;
    const int n0 = ((((x >> 2) & 1) << 8) | (x >> 3)) * 16;

    const __bf16* xb = xin + (size_t)b * NN * NC;
    const float4* pb = pT  + (size_t)b * NN;
    const float*  fb = (const float*)(wb + WTILES*64);

    int jv[4];
#pragma unroll
    for (int pp = 0; pp < 4; ++pp)
        jv[pp] = idx[((size_t)b*NN + n0 + wave*4 + pp)*NK + c0];

    // rel -> A-fragment directly; k=3 carries 1.0 to activate the bias row
    bf16x8 afr[4];
#pragma unroll
    for (int pp = 0; pp < 4; ++pp) {
        float4 pn = pb[n0 + wave*4 + pp];
        float4 pj = pb[jv[pp]];
#pragma unroll
        for (int k = 0; k < 8; ++k) afr[pp][k] = (__bf16)0.f;
        if (quad == 0) {
            afr[pp][0] = (__bf16)(pn.x - pj.x);
            afr[pp][1] = (__bf16)(pn.y - pj.y);
            afr[pp][2] = (__bf16)(pn.z - pj.z);
            afr[pp][3] = (__bf16)1.0f;
        }
    }

    // gx gathers in D-layout, direct bf16x4 loads; issued here so L2 latency
    // hides behind stage 1. Residual also hoisted here.
    bf16x4 gxb[4][4];
#pragma unroll
    for (int pt = 0; pt < 4; ++pt) {
        const __bf16* xr = &xb[(size_t)jv[pt] * NC];
#pragma unroll
        for (int ct = 0; ct < 4; ++ct)
            gxb[pt][ct] = *(const bf16x4*)&xr[ct*16 + quad*4];
    }
    bf16x4 resb = *(const bf16x4*)&xb[(size_t)(n0 + c0)*NC + wave*16 + quad*4];

    // ---- stage 1 (swapped): h1 = relu(W1 @ [rel;1] ), D=[ch][nb] ----
    {
        const f32x4 zf = {0.f, 0.f, 0.f, 0.f};
#pragma unroll
        for (int ct = 0; ct < 4; ++ct) {
            bf16x8 w = wb[(24+ct)*64 + lane];
#pragma unroll
            for (int pt = 0; pt < 4; ++pt) {
                f32x4 a = mfma16(w, afr[pt], zf);
                bf16x4 pk;
#pragma unroll
                for (int r = 0; r < 4; ++r) pk[r] = (__bf16)fmaxf(a[r], 0.f);
                *(bf16x4*)&sb[wave][pt][c0*72 + ct*16 + quad*4] = pk;
            }
        }
    }

    // ---- stage 2 (swapped): t = W2 @ h1 + b2 + gx (gx in acc init) ----
    {
        bf16x8 f0[4], f1[4];
#pragma unroll
        for (int pt = 0; pt < 4; ++pt) {
            f0[pt] = *(const bf16x8*)&sb[wave][pt][c0*72 + quad*8];
            f1[pt] = *(const bf16x8*)&sb[wave][pt][c0*72 + 32 + quad*8];
        }
#pragma unroll
        for (int ct = 0; ct < 4; ++ct) {
            bf16x8 w0 = wb[(0+ct)*64 + lane];
            bf16x8 w1 = wb[(4+ct)*64 + lane];
            float4 bv = *(const float4*)&fb[1*64 + ct*16 + quad*4];
#pragma unroll
            for (int pt = 0; pt < 4; ++pt) {
                f32x4 a;
#pragma unroll
                for (int r = 0; r < 4; ++r)
                    a[r] = ((const float*)&bv)[r] + (float)gxb[pt][ct][r];
                a = mfma16(w0, f0[pt], a);
                a = mfma16(w1, f1[pt], a);
                bf16x4 pk;
#pragma unroll
                for (int r = 0; r < 4; ++r) pk[r] = (__bf16)a[r];
                *(bf16x4*)&sb[wave][pt][c0*72 + ct*16 + quad*4] = pk;
            }
        }
    }

    // ---- stage 3 (swapped): a1 = relu(A1 @ t + b3) ----
    {
        bf16x8 f0[4], f1[4];
#pragma unroll
        for (int pt = 0; pt < 4; ++pt) {
            f0[pt] = *(const bf16x8*)&sb[wave][pt][c0*72 + quad*8];
            f1[pt] = *(const bf16x8*)&sb[wave][pt][c0*72 + 32 + quad*8];
        }
#pragma unroll
        for (int ct = 0; ct < 4; ++ct) {
            bf16x8 w0 = wb[( 8+ct)*64 + lane];
            bf16x8 w1 = wb[(12+ct)*64 + lane];
            float4 bv = *(const float4*)&fb[2*64 + ct*16 + quad*4];
#pragma unroll
            for (int pt = 0; pt < 4; ++pt) {
                f32x4 a;
#pragma unroll
                for (int r = 0; r < 4; ++r) a[r] = ((const float*)&bv)[r];
                a = mfma16(w0, f0[pt], a);
                a = mfma16(w1, f1[pt], a);
                bf16x4 pk;
#pragma unroll
                for (int r = 0; r < 4; ++r) pk[r] = (__bf16)fmaxf(a[r], 0.f);
                *(bf16x4*)&sb[wave][pt][c0*72 + ct*16 + quad*4] = pk;
            }
        }
    }

    // ---- stage 4 (normal): a2 = relu(A2 @ a1 + b4); max over nb ----
    {
        bf16x8 f0[4], f1[4];
#pragma unroll
        for (int pt = 0; pt < 4; ++pt) {
            f0[pt] = *(const bf16x8*)&sb[wave][pt][c0*72 + quad*8];
            f1[pt] = *(const bf16x8*)&sb[wave][pt][c0*72 + 32 + quad*8];
        }
        float mx[4][4];
#pragma unroll
        for (int ct = 0; ct < 4; ++ct) {
            bf16x8 w0 = wb[(16+ct)*64 + lane];
            bf16x8 w1 = wb[(20+ct)*64 + lane];
            float bc = fb[3*64 + ct*16 + c0];
#pragma unroll
            for (int pt = 0; pt < 4; ++pt) {
                f32x4 a;
#pragma unroll
                for (int r = 0; r < 4; ++r) a[r] = bc;
                a = mfma16(f0[pt], w0, a);
                a = mfma16(f1[pt], w1, a);
                float m = 0.f;  // relu floor
#pragma unroll
                for (int r = 0; r < 4; ++r) m = fmaxf(m, a[r]);
                mx[pt][ct] = m;
            }
        }
#pragma unroll
        for (int pt = 0; pt < 4; ++pt) {
            float m0 = mx[pt][0], m1 = mx[pt][1], m2 = mx[pt][2], m3 = mx[pt][3];
            m0 = fmaxf(m0, __shfl_xor(m0, 16, 64));
            m0 = fmaxf(m0, __shfl_xor(m0, 32, 64));
            m1 = fmaxf(m1, __shfl_xor(m1, 16, 64));
            m1 = fmaxf(m1, __shfl_xor(m1, 32, 64));
            m2 = fmaxf(m2, __shfl_xor(m2, 16, 64));
            m2 = fmaxf(m2, __shfl_xor(m2, 32, 64));
            m3 = fmaxf(m3, __shfl_xor(m3, 16, 64));
            m3 = fmaxf(m3, __shfl_xor(m3, 32, 64));
            float mq = (quad == 0) ? m0 : (quad == 1) ? m1 : (quad == 2) ? m2 : m3;
            yAll[(wave*4 + pt)*72 + quad*16 + c0] = (__bf16)mq;
        }
    }

    __syncthreads();

    // ---- down-proj (swapped): D=[ch][pt]; residual in acc init ----
    {
        bf16x8 y0  = *(const bf16x8*)&yAll[c0*72 + quad*8];
        bf16x8 y1  = *(const bf16x8*)&yAll[c0*72 + 32 + quad*8];
        bf16x8 lw0 = wb[(28 + wave*2 + 0)*64 + lane];
        bf16x8 lw1 = wb[(28 + wave*2 + 1)*64 + lane];
        float4 lb4 = *(const float4*)&fb[4*64 + wave*16 + quad*4];
        f32x4 a;
#pragma unroll
        for (int r = 0; r < 4; ++r)
            a[r] = ((const float*)&lb4)[r] + (float)resb[r];
        a = mfma16(lw0, y0, a);
        a = mfma16(lw1, y1, a);

        if (CHW) {
            float* out = (float*)outv;
#pragma unroll
            for (int r = 0; r < 4; ++r)
                out[((size_t)b*NC + wave*16 + quad*4 + r)*NN + n0 + c0] = a[r];
        } else {
            __bf16* out = (__bf16*)outv;
            bf16x4 pk;
#pragma unroll
            for (int r = 0; r < 4; ++r) pk[r] = (__bf16)a[r];
            *(bf16x4*)&out[((size_t)b*NN + n0 + c0)*NC + wave*16 + quad*4] = pk;
        }
    }
}

extern "C" void kernel_launch(void* const* d_in, const int* in_sizes, int n_in,
                              void* d_out, int out_size, void* d_ws, size_t ws_size,
                              hipStream_t stream) {
    (void)in_sizes; (void)n_in; (void)out_size; (void)ws_size;
    const float* p   = (const float*)d_in[0];
    const float* x   = (const float*)d_in[1];
    const int*   idx = (const int*)d_in[2];

    float*  pT  = (float*)d_ws;                              // NB*NN*4 floats
    __bf16* xT0 = (__bf16*)(pT + (size_t)NB*NN*4);           // NB*NN*NC bf16
    __bf16* xT1 = xT0 + (size_t)NB*NN*NC;                    // NB*NN*NC bf16
    bf16x8* wbuf = (bf16x8*)(xT1 + (size_t)NB*NN*NC);        // 2 * WBLK_UNITS

    float* out_p = (float*)d_out;                            // (B,3,N)
    float* out_x = out_p + (size_t)NB*3*NN;                  // (B,C,N)

    static const int strd[20] = {192,64,64,64, 4096,64,64,64,
                                 4096,64,64,64, 4096,64,64,64,
                                 4096,64,64,64};
    TwoParams PP;
    for (int i = 0; i < 20; ++i) {
        const float* base = (const float*)d_in[3+i];
        PP.p[0].a[i] = base;
        PP.p[1].a[i] = base + strd[i];
    }

    prep_all_kernel<<<642, 256, 0, stream>>>(p, x, PP, (float4*)pT, xT0, wbuf, out_p);
    pt_block_kernel<0><<<NB*NN/16, 256, 0, stream>>>((const float4*)pT, xT0, idx,
                                                     wbuf, (void*)xT1);
    pt_block_kernel<1><<<NB*NN/16, 256, 0, stream>>>((const float4*)pT, xT1, idx,
                                                     wbuf + WBLK_UNITS, (void*)out_x);
}